// Round 1
// baseline (615.294 us; speedup 1.0000x reference)
//
#include <hip/hip_runtime.h>
#include <stdint.h>

#define AS1 __attribute__((address_space(1)))
#define AS3 __attribute__((address_space(3)))

typedef __attribute__((ext_vector_type(8))) short bf16x8;
typedef __attribute__((ext_vector_type(4))) float f32x4;

// ---- helpers ----

__device__ inline unsigned short f2bf(float f) {
    uint32_t u = __float_as_uint(f);
    u += 0x7FFFu + ((u >> 16) & 1u);   // round-to-nearest-even
    return (unsigned short)(u >> 16);
}

// sign of e_a * e_b in Cl(4,1), metric [1,1,1,1,-1]
__device__ inline float gp_sign(int a, int b) {
    int s = __popc((a >> 1) & b) + __popc((a >> 2) & b) +
            __popc((a >> 3) & b) + __popc((a >> 4) & b);
    s += (a & b) >> 4;   // e4^2 = -1
    return (s & 1) ? -1.0f : 1.0f;
}

// ---- kernel 1: cast x (fp32 [2048,8192]) -> bf16 ----
__global__ __launch_bounds__(256) void cast_x_kernel(const float* __restrict__ x,
                                                     unsigned short* __restrict__ xb) {
    size_t t = (size_t)blockIdx.x * 256 + threadIdx.x;   // 2,097,152 threads, 8 elems each
    size_t base = t * 8;
    const float4* xp = (const float4*)(x + base);
    float4 a = xp[0], b = xp[1];
    union { unsigned short s[8]; uint4 v; } r;
    r.s[0] = f2bf(a.x); r.s[1] = f2bf(a.y); r.s[2] = f2bf(a.z); r.s[3] = f2bf(a.w);
    r.s[4] = f2bf(b.x); r.s[5] = f2bf(b.y); r.s[6] = f2bf(b.z); r.s[7] = f2bf(b.w);
    *((uint4*)(xb + base)) = r.v;
}

// ---- kernel 2: build W_bigT[(o*32+k), (i*32+l)] = bf16( w[o,i,l^k] * sgn(l^k,l) ) ----
__global__ __launch_bounds__(256) void build_wt_kernel(const float* __restrict__ w,
                                                       unsigned short* __restrict__ WT) {
    unsigned t = blockIdx.x * 256 + threadIdx.x;   // 8,388,608 threads, 8 elems each
    unsigned col8 = t & 1023;     // 16B chunk within row: covers (i, l0..l0+7)
    unsigned c = t >> 10;         // row index = o*32+k, 8192 rows
    unsigned k = c & 31;
    unsigned o = c >> 5;
    unsigned i = col8 >> 2;
    unsigned l0 = (col8 & 3) << 3;
    const float* wrow = w + ((size_t)o * 256 + i) * 32;
    union { unsigned short s[8]; uint4 v; } r;
#pragma unroll
    for (int u = 0; u < 8; ++u) {
        int l = (int)l0 + u;
        int j = l ^ (int)k;
        r.s[u] = f2bf(wrow[j] * gp_sign(j, l));
    }
    *((uint4*)(WT + (size_t)c * 8192 + (size_t)col8 * 8)) = r.v;
}

// ---- kernel 3: GEMM  C[2048,8192] = A[2048,8192] * B^T[8192,8192]  (bf16 in, fp32 out) ----
// m97 structure: 128x128 tile, BK=32, 4 waves (2x2 of 64x64), 16x16x32 MFMA, 4x4 tiles/wave
__global__ __launch_bounds__(256) void gemm_kernel(const unsigned short* __restrict__ A,
                                                   const unsigned short* __restrict__ B,
                                                   float* __restrict__ C) {
    const int N = 8192, K = 8192;
    __shared__ alignas(16) unsigned short As[128 * 32];
    __shared__ alignas(16) unsigned short Bs[128 * 32];

    int tid = threadIdx.x;
    int wid = tid >> 6, lane = tid & 63;
    int row0 = blockIdx.y * 128;   // M tiles (16)
    int col0 = blockIdx.x * 128;   // N tiles (64)
    int wr = (wid >> 1) * 64, wc = (wid & 1) * 64;
    int lm = lane & 15, quad = lane >> 4;

    f32x4 acc[4][4];
#pragma unroll
    for (int ti = 0; ti < 4; ++ti)
#pragma unroll
        for (int tj = 0; tj < 4; ++tj)
            acc[ti][tj] = (f32x4){0.f, 0.f, 0.f, 0.f};

    for (int k0 = 0; k0 < K; k0 += 32) {
        // stage 128x32 bf16 tiles of A and B via async global->LDS, 16B/lane
#pragma unroll
        for (int p = 0; p < 2; ++p) {
            int c = p * 256 + tid;        // chunk id 0..511
            int m = c >> 2;               // tile row
            int off = (c & 3) * 8;        // bf16 offset within row
            const unsigned short* ga = A + (size_t)(row0 + m) * K + k0 + off;
            const unsigned short* gb = B + (size_t)(col0 + m) * K + k0 + off;
            unsigned short* la = &As[(size_t)(p * 256 + wid * 64) * 8];  // wave-uniform base
            unsigned short* lb = &Bs[(size_t)(p * 256 + wid * 64) * 8];
            __builtin_amdgcn_global_load_lds((const AS1 void*)ga, (AS3 void*)la, 16, 0, 0);
            __builtin_amdgcn_global_load_lds((const AS1 void*)gb, (AS3 void*)lb, 16, 0, 0);
        }
        __syncthreads();

        bf16x8 af[4], bfr[4];
#pragma unroll
        for (int ti = 0; ti < 4; ++ti)
            af[ti] = *(const bf16x8*)&As[(wr + ti * 16 + lm) * 32 + quad * 8];
#pragma unroll
        for (int tj = 0; tj < 4; ++tj)
            bfr[tj] = *(const bf16x8*)&Bs[(wc + tj * 16 + lm) * 32 + quad * 8];
#pragma unroll
        for (int ti = 0; ti < 4; ++ti)
#pragma unroll
            for (int tj = 0; tj < 4; ++tj)
                acc[ti][tj] = __builtin_amdgcn_mfma_f32_16x16x32_bf16(af[ti], bfr[tj],
                                                                      acc[ti][tj], 0, 0, 0);
        __syncthreads();
    }

    // epilogue: C/D layout col=lane&15, row=quad*4+reg
#pragma unroll
    for (int ti = 0; ti < 4; ++ti)
#pragma unroll
        for (int tj = 0; tj < 4; ++tj)
#pragma unroll
            for (int r = 0; r < 4; ++r) {
                int row = row0 + wr + ti * 16 + quad * 4 + r;
                int col = col0 + wc + tj * 16 + lm;
                C[(size_t)row * N + col] = acc[ti][tj][r];
            }
}

// ---- kernel 4: in-place normalize over each contiguous 32-float group ----
__global__ __launch_bounds__(256) void normalize_kernel(float* __restrict__ out) {
    size_t t = (size_t)blockIdx.x * 256 + threadIdx.x;   // 4,194,304 float4s
    float4 v = ((const float4*)out)[t];
    float ss = v.x * v.x + v.y * v.y + v.z * v.z + v.w * v.w;
    ss += __shfl_xor(ss, 1);
    ss += __shfl_xor(ss, 2);
    ss += __shfl_xor(ss, 4);
    float inv = rsqrtf(ss + 1e-6f);
    v.x *= inv; v.y *= inv; v.z *= inv; v.w *= inv;
    ((float4*)out)[t] = v;
}

extern "C" void kernel_launch(void* const* d_in, const int* in_sizes, int n_in,
                              void* d_out, int out_size, void* d_ws, size_t ws_size,
                              hipStream_t stream) {
    const float* x = (const float*)d_in[0];   // [4,512,256,32]
    const float* w = (const float*)d_in[1];   // [256,256,32]
    float* out = (float*)d_out;               // [4,512,256,32]

    unsigned short* xb = (unsigned short*)d_ws;                           // 33,554,432 B
    unsigned short* WT = (unsigned short*)((char*)d_ws + 33554432);       // 134,217,728 B

    hipLaunchKernelGGL(cast_x_kernel,   dim3(8192),    dim3(256), 0, stream, x, xb);
    hipLaunchKernelGGL(build_wt_kernel, dim3(32768),   dim3(256), 0, stream, w, WT);
    hipLaunchKernelGGL(gemm_kernel,     dim3(64, 16),  dim3(256), 0, stream, xb, WT, out);
    hipLaunchKernelGGL(normalize_kernel, dim3(16384),  dim3(256), 0, stream, out);
}